// Round 14
// baseline (1428.661 us; speedup 1.0000x reference)
//
#include <hip/hip_runtime.h>
#include <math.h>

#define NX 192
#define NY 192
#define NZ 96
#define NV 4
#define VOL (NZ * NY * NX)      /* 3,538,944 */
#define NTOT (NV * VOL)         /* 14,155,776 */
#define YS NX
#define ZS (NY * NX)

#define TX 48
#define TYB 24                   /* y tile (24 rows, 28 live row-lanes of 32) */
#define NG 14                    /* x groups incl halo 4 */
#define R2A 30                   /* A rows: halo 3 */
#define RROW 28                  /* E1/ZM rows: halo 2 */
#define ZCHM 12                  /* 8 z-chunks */
#define NCH 8

#define SLOT4(x) (((x) + 100) % 4)
#define SLOT3(x) (((x) + 99) % 3)
#define SLOT2(x) (((x) + 100) % 2)

#define HINF  0x7C00u
#define HNINF 0xFC00u

typedef _Float16 h2v __attribute__((ext_vector_type(2)));

struct __align__(8) H4u { unsigned lo, hi; };

__device__ __forceinline__ h2v h2_of(unsigned u) { return __builtin_bit_cast(h2v, u); }
__device__ __forceinline__ unsigned u_of(h2v h) { return __builtin_bit_cast(unsigned, h); }

__device__ __forceinline__ H4u h4min(H4u a, H4u b) {
    H4u r;
    r.lo = u_of(__builtin_elementwise_min(h2_of(a.lo), h2_of(b.lo)));
    r.hi = u_of(__builtin_elementwise_min(h2_of(a.hi), h2_of(b.hi)));
    return r;
}
__device__ __forceinline__ H4u h4max(H4u a, H4u b) {
    H4u r;
    r.lo = u_of(__builtin_elementwise_max(h2_of(a.lo), h2_of(b.lo)));
    r.hi = u_of(__builtin_elementwise_max(h2_of(a.hi), h2_of(b.hi)));
    return r;
}
__device__ __forceinline__ H4u h4add(H4u a, H4u b) {
    H4u r;
    r.lo = u_of(h2_of(a.lo) + h2_of(b.lo));
    r.hi = u_of(h2_of(a.hi) + h2_of(b.hi));
    return r;
}
__device__ __forceinline__ H4u h4sub(H4u a, H4u b) {
    H4u r;
    r.lo = u_of(h2_of(a.lo) - h2_of(b.lo));
    r.hi = u_of(h2_of(a.hi) - h2_of(b.hi));
    return r;
}
__device__ __forceinline__ H4u h4mul(H4u a, H4u b) {
    H4u r;
    r.lo = u_of(h2_of(a.lo) * h2_of(b.lo));
    r.hi = u_of(h2_of(a.hi) * h2_of(b.hi));
    return r;
}
/* skel update: s += max(relu(a-dil)*(1-s), 0), packed fp16 */
__device__ __forceinline__ H4u h4skel(H4u s, H4u a, H4u dil) {
    const H4u HZ4 = { 0u, 0u };
    const H4u HONE = { 0x3C003C00u, 0x3C003C00u };
    H4u dd = h4max(h4sub(a, dil), HZ4);
    H4u t = h4mul(dd, h4sub(HONE, s));
    return h4add(s, h4max(t, HZ4));
}
__device__ __forceinline__ H4u shl1(H4u c, unsigned p16) {
    H4u r;
    r.lo = (c.lo << 16) | (p16 & 0xFFFFu);
    r.hi = (c.hi << 16) | (c.lo >> 16);
    return r;
}
__device__ __forceinline__ H4u shr1(H4u c, unsigned n16) {
    H4u r;
    r.lo = (c.lo >> 16) | (c.hi << 16);
    r.hi = (c.hi >> 16) | ((n16 & 0xFFFFu) << 16);
    return r;
}
__device__ __forceinline__ H4u f4_to_h4(float4 f) {
    h2v a, b;
    a[0] = (_Float16)f.x; a[1] = (_Float16)f.y;
    b[0] = (_Float16)f.z; b[1] = (_Float16)f.w;
    H4u r; r.lo = u_of(a); r.hi = u_of(b); return r;
}
__device__ __forceinline__ float4 h4_to_f4(H4u h) {
    h2v a = h2_of(h.lo), b = h2_of(h.hi);
    return make_float4((float)a[0], (float)a[1], (float)b[0], (float)b[1]);
}

// ---------------- double-round kernel (r12-verified dataflow, 512-thread
// blocks, 32 waves/CU) ------------------------------------------------------
// Skewed pipeline, 1 barrier/step: E1(z+1), {E2+upd1}(z-1), upd2(z-3).
template<bool FIRST>
__global__ __launch_bounds__(512, 8) void fused2_kernel(
    const float* __restrict__ pred, const float* __restrict__ target,
    const _Float16* __restrict__ Ain, _Float16* __restrict__ Eout,
    _Float16* __restrict__ skel)
{
    __shared__ H4u As[4][R2A][NG];
    __shared__ H4u E1c[3][RROW][NG];
    __shared__ H4u ZM1[2][RROW][NG];
    __shared__ H4u ZM2[2][RROW][NG];

    const int tid = threadIdx.x;
    const int lr  = tid >> 4;               /* row lane 0..31 (0..27 live) */
    const int c   = tid & 15;
    const int cc  = (c < 14) ? c : 13;
    const int lre = (lr < RROW) ? lr : (RROW - 1);
    const int sr  = tid / 14;               /* stage row 0..36 (<30 live) */
    const int sg  = tid - sr * 14;

    const int x0 = blockIdx.x * TX;
    const int y0 = blockIdx.y * TYB;
    const int v  = blockIdx.z / NCH;
    const int ch = blockIdx.z % NCH;
    const int z0 = ch * ZCHM;
    const int z1 = z0 + ZCHM;

    const float* Af = nullptr;
    const _Float16* Ah = nullptr;
    if (FIRST) Af = ((v < 2) ? pred : target) + (size_t)((v & 1) * 2 + 1) * VOL;
    else       Ah = Ain + (size_t)v * VOL;
    _Float16* Ev = Eout + (size_t)v * VOL;
    _Float16* Sv = skel + (size_t)v * VOL;

    const H4u HP4 = { 0x7C007C00u, 0x7C007C00u };
    const H4u HN4 = { 0xFC00FC00u, 0xFC00FC00u };
    const H4u HZ4 = { 0u, 0u };

    const bool xlo = (x0 == 0);
    const bool xhi = (x0 + TX == NX);

    const int  gys  = y0 - 3 + sr;
    const int  gxs  = x0 - 4 + 4 * sg;
    const bool stIn = (sr < R2A) && (gys >= 0) && (gys < NY) &&
                      (gxs >= 0) && (gxs < NX);

    const int  gx   = x0 - 4 + 4 * c;
    const bool gxin = (c < 14) && (gx >= 0) && (gx < NX);
    const int  gyo  = y0 - 2 + lre;         /* own absolute row (clamped) */
    const bool yIn  = (gyo >= 0) && (gyo < NY);
    const bool uAct = (lr >= 2 && lr <= 25 && c >= 1 && c <= 12);
    const int  rdn  = (lre > 0) ? lre - 1 : 0;
    const int  rup  = (lre < RROW - 1) ? lre + 1 : (RROW - 1);

    auto stageLoad = [&](int za) -> H4u {
        H4u val = HP4;
        if (stIn && za >= 0 && za < NZ) {
            if (FIRST)
                val = f4_to_h4(*(const float4*)(Af + (size_t)za * ZS + gys * YS + gxs));
            else
                val = *(const H4u*)(Ah + (size_t)za * ZS + gys * YS + gxs);
        }
        return val;
    };
    auto stageWrite = [&](int za, H4u val) {
        if (sr < R2A) As[SLOT4(za)][sr][sg] = val;
    };

    auto e1compute = [&](int zp, H4u& cenOut) -> H4u {
        if (zp >= NZ) { cenOut = HP4; return HP4; }
        const int s_c = SLOT4(zp), s_m = SLOT4(zp - 1), s_p = SLOT4(zp + 1);
        const bool hp = (zp + 1 < NZ);
        const int ar = lre + 1;
        H4u cen = As[s_c][ar][cc];
        H4u ylo = As[s_c][ar - 1][cc];
        H4u yhi = As[s_c][ar + 1][cc];
        H4u zlo = As[s_m][ar][cc];
        H4u zhi = hp ? As[s_p][ar][cc] : HP4;
        cenOut = cen;
        unsigned lw = __shfl_up(cen.hi, 1) >> 16;
        unsigned rx = __shfl_down(cen.lo, 1) & 0xFFFFu;
        if (c == 0) lw = HINF;
        H4u m = h4min(cen, shl1(cen, lw));
        m = h4min(m, shr1(cen, rx));
        m = h4min(m, h4min(ylo, yhi));
        m = h4min(m, h4min(zlo, zhi));
        if (zp < 0 || !yIn || !gxin) m = HP4;
        if (lr < RROW && c < 14) E1c[SLOT3(zp)][lr][c] = m;
        return m;
    };

    // ---- prologue ----
    stageWrite(z0 - 3, stageLoad(z0 - 3));
    stageWrite(z0 - 2, stageLoad(z0 - 2));
    stageWrite(z0 - 1, stageLoad(z0 - 1));
    stageWrite(z0,     stageLoad(z0));
    __syncthreads();
    H4u aT, a1, a2 = HP4;
    H4u e1m2 = e1compute(z0 - 2, aT);
    H4u e1m1 = e1compute(z0 - 1, aT);
    __syncthreads();
    stageWrite(z0 + 1, stageLoad(z0 + 1));
    __syncthreads();
    H4u e1c = e1compute(z0, a1);
    stageWrite(z0 + 2, stageLoad(z0 + 2));
    __syncthreads();

    H4u e1m3 = HP4;
    H4u e2c = HN4, e2m1 = HN4;
    H4u zm1_prev = HN4, zm2_prev = HN4;
    H4u skA = HZ4, sq1 = HZ4, sq2 = HZ4;

    // ---- main loop: one barrier per step ----
    for (int z = z0; z <= z1 + 2; ++z) {
        const bool doStage = (z <= z1 - 1);
        H4u stv = doStage ? stageLoad(z + 3) : HP4;
        H4u skN = HZ4;
        if (!FIRST && z < z1 && uAct)
            skN = *(const H4u*)(Sv + (size_t)z * ZS + gyo * YS + gx);

        H4u aC = HP4;
        H4u e1new = (z <= z1) ? e1compute(z + 1, aC) : HP4;

        H4u zm1w;
        {
            H4u t0 = (z >= 1) ? e1m1 : HN4;
            H4u t2 = (z + 1 < NZ) ? e1new : HN4;
            zm1w = h4max(t0, h4max(e1c, t2));
            if (!yIn || !gxin) zm1w = HN4;
            if (lr < RROW && c < 14) ZM1[SLOT2(z)][lr][c] = zm1w;
        }

        const int p = z - 1;
        H4u e2new = HN4;
        if (p >= 0 && p <= z1 && p < NZ) {
            H4u cen = e1m1;
            H4u zlo = e1m2;
            H4u zhi = e1c;
            H4u ylo = E1c[SLOT3(p)][rdn][cc];
            H4u yhi = E1c[SLOT3(p)][rup][cc];
            unsigned lwE = __shfl_up(cen.hi, 1) >> 16;
            unsigned rxE = __shfl_down(cen.lo, 1) & 0xFFFFu;
            if (c == 0) lwE = HINF;
            H4u m2 = h4min(cen, shl1(cen, lwE));
            m2 = h4min(m2, shr1(cen, rxE));
            m2 = h4min(m2, h4min(ylo, yhi));
            m2 = h4min(m2, h4min(zlo, zhi));
            if (yIn && gxin) {
                e2new = m2;
                if (p >= z0 && p < z1 && lr >= 2 && lr <= 25 && c >= 1 && c <= 12)
                    *(H4u*)(Ev + (size_t)p * ZS + gyo * YS + gx) = m2;
            }
        }

        H4u zm2w = h4max(e2m1, h4max(e2c, e2new));
        if (lr < RROW && c < 14) ZM2[SLOT2(z - 2)][lr][c] = zm2w;

        H4u spnew = HZ4;
        if (p >= z0 && p < z1) {
            H4u vm = h4max(ZM1[SLOT2(p)][rdn][cc],
                     h4max(zm1_prev, ZM1[SLOT2(p)][rup][cc]));
            unsigned lw = __shfl_up(vm.hi, 1) >> 16;
            unsigned rx = __shfl_down(vm.lo, 1) & 0xFFFFu;
            if (xlo && c == 1)  lw = HNINF;
            if (xhi && c == 12) rx = HNINF;
            if (uAct) {
                H4u dilh = h4max(h4max(shl1(vm, lw), vm), shr1(vm, rx));
                spnew = h4skel(skA, a2, dilh);
            }
        }

        const int q = z - 3;
        if (q >= z0 && q < z1) {
            H4u vm2 = h4max(ZM2[SLOT2(q)][rdn][cc],
                      h4max(zm2_prev, ZM2[SLOT2(q)][rup][cc]));
            unsigned lw = __shfl_up(vm2.hi, 1) >> 16;
            unsigned rx = __shfl_down(vm2.lo, 1) & 0xFFFFu;
            if (xlo && c == 1)  lw = HNINF;
            if (xhi && c == 12) rx = HNINF;
            if (uAct) {
                H4u dilh = h4max(h4max(shl1(vm2, lw), vm2), shr1(vm2, rx));
                H4u s = h4skel(sq2, e1m3, dilh);
                *(H4u*)(Sv + (size_t)q * ZS + gyo * YS + gx) = s;
            }
        }

        if (doStage) stageWrite(z + 3, stv);

        __syncthreads();
        e1m3 = e1m2; e1m2 = e1m1; e1m1 = e1c; e1c = e1new;
        e2m1 = e2c; e2c = e2new;
        zm1_prev = zm1w; zm2_prev = zm2w;
        a2 = a1; a1 = aC;
        sq2 = sq1; sq1 = spnew; skA = skN;
    }
}

// ---------------- LAST kernel (round 50 + fused reduction), 512-thread -----
__global__ __launch_bounds__(512, 8) void last_kernel(
    const _Float16* __restrict__ Ain,
    const float* __restrict__ pred, const float* __restrict__ target,
    const _Float16* __restrict__ skel, double* __restrict__ sums)
{
    __shared__ H4u As[4][R2A][NG];
    __shared__ H4u ZM1[2][RROW][NG];
    __shared__ double sred[16];

    const int tid = threadIdx.x;
    const int lr  = tid >> 4;
    const int c   = tid & 15;
    const int cc  = (c < 14) ? c : 13;
    const int lre = (lr < RROW) ? lr : (RROW - 1);
    const int sr  = tid / 14;
    const int sg  = tid - sr * 14;

    const int x0 = blockIdx.x * TX;
    const int y0 = blockIdx.y * TYB;
    const int v  = blockIdx.z / NCH;
    const int ch = blockIdx.z % NCH;
    const int z0 = ch * ZCHM;
    const int z1 = z0 + ZCHM;

    const _Float16* Ah = Ain + (size_t)v * VOL;
    const _Float16* Sv = skel + (size_t)v * VOL;
    const float* Ov = ((v < 2) ? target : pred) + (size_t)((v & 1) * 2 + 1) * VOL;

    const H4u HP4 = { 0x7C007C00u, 0x7C007C00u };
    const H4u HN4 = { 0xFC00FC00u, 0xFC00FC00u };
    const H4u HZ4 = { 0u, 0u };
    const float4 ZERO4 = make_float4(0.f, 0.f, 0.f, 0.f);

    const bool xlo = (x0 == 0);
    const bool xhi = (x0 + TX == NX);

    const int  gys  = y0 - 3 + sr;
    const int  gxs  = x0 - 4 + 4 * sg;
    const bool stIn = (sr < R2A) && (gys >= 0) && (gys < NY) &&
                      (gxs >= 0) && (gxs < NX);

    const int  gx   = x0 - 4 + 4 * c;
    const bool gxin = (c < 14) && (gx >= 0) && (gx < NX);
    const int  gyo  = y0 - 2 + lre;
    const bool yIn  = (gyo >= 0) && (gyo < NY);
    const bool uAct = (lr >= 2 && lr <= 25 && c >= 1 && c <= 12);
    const int  rdn  = (lre > 0) ? lre - 1 : 0;
    const int  rup  = (lre < RROW - 1) ? lre + 1 : (RROW - 1);

    auto stageLoad = [&](int za) -> H4u {
        H4u val = HP4;
        if (stIn && za >= 0 && za < NZ)
            val = *(const H4u*)(Ah + (size_t)za * ZS + gys * YS + gxs);
        return val;
    };
    auto stageWrite = [&](int za, H4u val) {
        if (sr < R2A) As[SLOT4(za)][sr][sg] = val;
    };

    auto e1compute = [&](int zp, H4u& cenOut) -> H4u {
        if (zp >= NZ) { cenOut = HP4; return HP4; }
        const int s_c = SLOT4(zp), s_m = SLOT4(zp - 1), s_p = SLOT4(zp + 1);
        const bool hp = (zp + 1 < NZ);
        const int ar = lre + 1;
        H4u cen = As[s_c][ar][cc];
        H4u ylo = As[s_c][ar - 1][cc];
        H4u yhi = As[s_c][ar + 1][cc];
        H4u zlo = As[s_m][ar][cc];
        H4u zhi = hp ? As[s_p][ar][cc] : HP4;
        cenOut = cen;
        unsigned lw = __shfl_up(cen.hi, 1) >> 16;
        unsigned rx = __shfl_down(cen.lo, 1) & 0xFFFFu;
        if (c == 0) lw = HINF;
        H4u m = h4min(cen, shl1(cen, lw));
        m = h4min(m, shr1(cen, rx));
        m = h4min(m, h4min(ylo, yhi));
        m = h4min(m, h4min(zlo, zhi));
        if (zp < 0 || !yIn || !gxin) m = HP4;
        return m;
    };

    stageWrite(z0 - 2, stageLoad(z0 - 2));
    stageWrite(z0 - 1, stageLoad(z0 - 1));
    stageWrite(z0,     stageLoad(z0));
    stageWrite(z0 + 1, stageLoad(z0 + 1));
    __syncthreads();
    H4u aT, a1, a2 = HP4;
    H4u e1m1 = e1compute(z0 - 1, aT);
    H4u e1c  = e1compute(z0, a1);
    __syncthreads();
    stageWrite(z0 + 2, stageLoad(z0 + 2));
    __syncthreads();

    H4u zmP = HN4;
    H4u skA = HZ4;
    float4 oA = ZERO4;
    double afd = 0.0, afs = 0.0;

    for (int z = z0; z <= z1; ++z) {
        const bool doStage = (z <= z1 - 2);
        H4u stv = doStage ? stageLoad(z + 3) : HP4;
        H4u skN = HZ4;
        float4 oN = ZERO4;
        if (z < z1 && uAct) {
            skN = *(const H4u*)(Sv + (size_t)z * ZS + gyo * YS + gx);
            oN  = *(const float4*)(Ov + (size_t)z * ZS + gyo * YS + gx);
        }

        H4u aC = HP4;
        H4u e1new = (z + 1 <= z1) ? e1compute(z + 1, aC) : HP4;

        H4u zm1w = HN4;
        if (z <= z1 - 1) {
            H4u t0 = (z >= 1) ? e1m1 : HN4;
            H4u t2 = (z + 1 < NZ) ? e1new : HN4;
            zm1w = h4max(t0, h4max(e1c, t2));
            if (!yIn || !gxin) zm1w = HN4;
            if (lr < RROW && c < 14) ZM1[SLOT2(z)][lr][c] = zm1w;
        }

        const int p = z - 1;
        if (p >= z0 && p < z1) {
            H4u vm = h4max(ZM1[SLOT2(p)][rdn][cc],
                     h4max(zmP, ZM1[SLOT2(p)][rup][cc]));
            unsigned lw = __shfl_up(vm.hi, 1) >> 16;
            unsigned rx = __shfl_down(vm.lo, 1) & 0xFFFFu;
            if (xlo && c == 1)  lw = HNINF;
            if (xhi && c == 12) rx = HNINF;
            if (uAct) {
                H4u dilh = h4max(h4max(shl1(vm, lw), vm), shr1(vm, rx));
                H4u s = h4skel(skA, a2, dilh);
                float4 sf = h4_to_f4(s);
                afd += (double)(sf.x * oA.x + sf.y * oA.y +
                                sf.z * oA.z + sf.w * oA.w);
                afs += (double)(sf.x + sf.y + sf.z + sf.w);
            }
        }

        if (doStage) stageWrite(z + 3, stv);

        __syncthreads();
        e1m1 = e1c; e1c = e1new;
        a2 = a1; a1 = aC;
        zmP = zm1w;
        skA = skN; oA = oN;
    }

#pragma unroll
    for (int off = 32; off > 0; off >>= 1) {
        afd += __shfl_down(afd, off, 64);
        afs += __shfl_down(afs, off, 64);
    }
    int lane = tid & 63, wid = tid >> 6;
    if (lane == 0) { sred[wid * 2] = afd; sred[wid * 2 + 1] = afs; }
    __syncthreads();
    if (tid == 0) {
        double fd = 0.0, fs = 0.0;
#pragma unroll
        for (int w = 0; w < 8; ++w) { fd += sred[w * 2]; fs += sred[w * 2 + 1]; }
        if (v < 2) { atomicAdd(&sums[0], fd); atomicAdd(&sums[1], fs); }
        else       { atomicAdd(&sums[2], fd); atomicAdd(&sums[3], fs); }
    }
}

__global__ void final_kernel(const double* __restrict__ sums,
                             float* __restrict__ out) {
    if (threadIdx.x == 0 && blockIdx.x == 0) {
        const double SM = 1e-5;
        double tprec = (sums[0] + SM) / (sums[1] + SM);
        double tsens = (sums[2] + SM) / (sums[3] + SM);
        double cl = 2.0 * tprec * tsens / (tprec + tsens + SM);
        out[0] = (float)(1.0 - cl);
    }
}

extern "C" void kernel_launch(void* const* d_in, const int* in_sizes, int n_in,
                              void* d_out, int out_size, void* d_ws, size_t ws_size,
                              hipStream_t stream) {
    const float* pred = (const float*)d_in[0];
    const float* target = (const float*)d_in[1];
    float* out = (float*)d_out;

    _Float16* H0 = (_Float16*)d_ws;
    _Float16* H1 = H0 + NTOT;
    _Float16* skel = H1 + NTOT;
    double* sums = (double*)(skel + NTOT);

    hipMemsetAsync(sums, 0, 4 * sizeof(double), stream);

    dim3 g(NX / TX, NY / TYB, NV * NCH);     /* 4 x 8 x 32 = 1024 blocks */

    /* rounds 0,1: FIRST (reads pred/target channels directly) */
    fused2_kernel<true><<<g, 512, 0, stream>>>(pred, target, H0, H0, skel);
    /* rounds 2..49: 24 double launches */
    _Float16* A = H0;
    _Float16* B = H1;
    for (int j = 0; j < 24; ++j) {
        fused2_kernel<false><<<g, 512, 0, stream>>>(pred, target, A, B, skel);
        _Float16* t = A; A = B; B = t;
    }
    /* round 50 + fused reduction */
    last_kernel<<<g, 512, 0, stream>>>(A, pred, target, skel, sums);

    final_kernel<<<1, 64, 0, stream>>>(sums, out);
}

// Round 15
// 1426.088 us; speedup vs baseline: 1.0018x; 1.0018x over previous
//
#include <hip/hip_runtime.h>
#include <math.h>

#define NX 192
#define NY 192
#define NZ 96
#define NV 4
#define VOL (NZ * NY * NX)      /* 3,538,944 */
#define NTOT (NV * VOL)         /* 14,155,776 */
#define YS NX
#define ZS (NY * NX)

#define TX 48
#define TYB 24                   /* y tile (24 rows, 28 live row-lanes of 32) */
#define NG 14                    /* x groups incl halo 4 */
#define R2A 30                   /* A rows: halo 3 */
#define RROW 28                  /* E1/ZM rows: halo 2 */
#define ZCHM 12                  /* 8 z-chunks */
#define NCH 8

#define SLOT4(x) (((x) + 100) % 4)
#define SLOT3(x) (((x) + 99) % 3)
#define SLOT2(x) (((x) + 100) % 2)

#define HINF  0x7C00u
#define HNINF 0xFC00u

typedef _Float16 h2v __attribute__((ext_vector_type(2)));

struct __align__(8) H4u { unsigned lo, hi; };

__device__ __forceinline__ h2v h2_of(unsigned u) { return __builtin_bit_cast(h2v, u); }
__device__ __forceinline__ unsigned u_of(h2v h) { return __builtin_bit_cast(unsigned, h); }

/* LDS-only barrier: drains LDS (cross-wave visibility) but leaves global
   loads/stores in flight across the barrier (they are wave-private here).
   __syncthreads would emit s_waitcnt vmcnt(0) and serialize HBM latency
   into every pipeline step. (m201-verified pattern.) */
__device__ __forceinline__ void ldsbar() {
    asm volatile("s_waitcnt lgkmcnt(0)" ::: "memory");
    __builtin_amdgcn_s_barrier();
}

__device__ __forceinline__ H4u h4min(H4u a, H4u b) {
    H4u r;
    r.lo = u_of(__builtin_elementwise_min(h2_of(a.lo), h2_of(b.lo)));
    r.hi = u_of(__builtin_elementwise_min(h2_of(a.hi), h2_of(b.hi)));
    return r;
}
__device__ __forceinline__ H4u h4max(H4u a, H4u b) {
    H4u r;
    r.lo = u_of(__builtin_elementwise_max(h2_of(a.lo), h2_of(b.lo)));
    r.hi = u_of(__builtin_elementwise_max(h2_of(a.hi), h2_of(b.hi)));
    return r;
}
__device__ __forceinline__ H4u h4add(H4u a, H4u b) {
    H4u r;
    r.lo = u_of(h2_of(a.lo) + h2_of(b.lo));
    r.hi = u_of(h2_of(a.hi) + h2_of(b.hi));
    return r;
}
__device__ __forceinline__ H4u h4sub(H4u a, H4u b) {
    H4u r;
    r.lo = u_of(h2_of(a.lo) - h2_of(b.lo));
    r.hi = u_of(h2_of(a.hi) - h2_of(b.hi));
    return r;
}
__device__ __forceinline__ H4u h4mul(H4u a, H4u b) {
    H4u r;
    r.lo = u_of(h2_of(a.lo) * h2_of(b.lo));
    r.hi = u_of(h2_of(a.hi) * h2_of(b.hi));
    return r;
}
/* skel update: s += max(relu(a-dil)*(1-s), 0), packed fp16 */
__device__ __forceinline__ H4u h4skel(H4u s, H4u a, H4u dil) {
    const H4u HZ4 = { 0u, 0u };
    const H4u HONE = { 0x3C003C00u, 0x3C003C00u };
    H4u dd = h4max(h4sub(a, dil), HZ4);
    H4u t = h4mul(dd, h4sub(HONE, s));
    return h4add(s, h4max(t, HZ4));
}
__device__ __forceinline__ H4u shl1(H4u c, unsigned p16) {
    H4u r;
    r.lo = (c.lo << 16) | (p16 & 0xFFFFu);
    r.hi = (c.hi << 16) | (c.lo >> 16);
    return r;
}
__device__ __forceinline__ H4u shr1(H4u c, unsigned n16) {
    H4u r;
    r.lo = (c.lo >> 16) | (c.hi << 16);
    r.hi = (c.hi >> 16) | ((n16 & 0xFFFFu) << 16);
    return r;
}
__device__ __forceinline__ H4u f4_to_h4(float4 f) {
    h2v a, b;
    a[0] = (_Float16)f.x; a[1] = (_Float16)f.y;
    b[0] = (_Float16)f.z; b[1] = (_Float16)f.w;
    H4u r; r.lo = u_of(a); r.hi = u_of(b); return r;
}
__device__ __forceinline__ float4 h4_to_f4(H4u h) {
    h2v a = h2_of(h.lo), b = h2_of(h.hi);
    return make_float4((float)a[0], (float)a[1], (float)b[0], (float)b[1]);
}

// ---------------- double-round kernel (r14-verified dataflow, LDS-only
// barriers) -----------------------------------------------------------------
// Skewed pipeline, 1 barrier/step: E1(z+1), {E2+upd1}(z-1), upd2(z-3).
template<bool FIRST>
__global__ __launch_bounds__(512, 8) void fused2_kernel(
    const float* __restrict__ pred, const float* __restrict__ target,
    const _Float16* __restrict__ Ain, _Float16* __restrict__ Eout,
    _Float16* __restrict__ skel)
{
    __shared__ H4u As[4][R2A][NG];
    __shared__ H4u E1c[3][RROW][NG];
    __shared__ H4u ZM1[2][RROW][NG];
    __shared__ H4u ZM2[2][RROW][NG];

    const int tid = threadIdx.x;
    const int lr  = tid >> 4;               /* row lane 0..31 (0..27 live) */
    const int c   = tid & 15;
    const int cc  = (c < 14) ? c : 13;
    const int lre = (lr < RROW) ? lr : (RROW - 1);
    const int sr  = tid / 14;               /* stage row 0..36 (<30 live) */
    const int sg  = tid - sr * 14;

    const int x0 = blockIdx.x * TX;
    const int y0 = blockIdx.y * TYB;
    const int v  = blockIdx.z / NCH;
    const int ch = blockIdx.z % NCH;
    const int z0 = ch * ZCHM;
    const int z1 = z0 + ZCHM;

    const float* Af = nullptr;
    const _Float16* Ah = nullptr;
    if (FIRST) Af = ((v < 2) ? pred : target) + (size_t)((v & 1) * 2 + 1) * VOL;
    else       Ah = Ain + (size_t)v * VOL;
    _Float16* Ev = Eout + (size_t)v * VOL;
    _Float16* Sv = skel + (size_t)v * VOL;

    const H4u HP4 = { 0x7C007C00u, 0x7C007C00u };
    const H4u HN4 = { 0xFC00FC00u, 0xFC00FC00u };
    const H4u HZ4 = { 0u, 0u };

    const bool xlo = (x0 == 0);
    const bool xhi = (x0 + TX == NX);

    const int  gys  = y0 - 3 + sr;
    const int  gxs  = x0 - 4 + 4 * sg;
    const bool stIn = (sr < R2A) && (gys >= 0) && (gys < NY) &&
                      (gxs >= 0) && (gxs < NX);

    const int  gx   = x0 - 4 + 4 * c;
    const bool gxin = (c < 14) && (gx >= 0) && (gx < NX);
    const int  gyo  = y0 - 2 + lre;         /* own absolute row (clamped) */
    const bool yIn  = (gyo >= 0) && (gyo < NY);
    const bool uAct = (lr >= 2 && lr <= 25 && c >= 1 && c <= 12);
    const int  rdn  = (lre > 0) ? lre - 1 : 0;
    const int  rup  = (lre < RROW - 1) ? lre + 1 : (RROW - 1);

    auto stageLoad = [&](int za) -> H4u {
        H4u val = HP4;
        if (stIn && za >= 0 && za < NZ) {
            if (FIRST)
                val = f4_to_h4(*(const float4*)(Af + (size_t)za * ZS + gys * YS + gxs));
            else
                val = *(const H4u*)(Ah + (size_t)za * ZS + gys * YS + gxs);
        }
        return val;
    };
    auto stageWrite = [&](int za, H4u val) {
        if (sr < R2A) As[SLOT4(za)][sr][sg] = val;
    };

    auto e1compute = [&](int zp, H4u& cenOut) -> H4u {
        if (zp >= NZ) { cenOut = HP4; return HP4; }
        const int s_c = SLOT4(zp), s_m = SLOT4(zp - 1), s_p = SLOT4(zp + 1);
        const bool hp = (zp + 1 < NZ);
        const int ar = lre + 1;
        H4u cen = As[s_c][ar][cc];
        H4u ylo = As[s_c][ar - 1][cc];
        H4u yhi = As[s_c][ar + 1][cc];
        H4u zlo = As[s_m][ar][cc];
        H4u zhi = hp ? As[s_p][ar][cc] : HP4;
        cenOut = cen;
        unsigned lw = __shfl_up(cen.hi, 1) >> 16;
        unsigned rx = __shfl_down(cen.lo, 1) & 0xFFFFu;
        if (c == 0) lw = HINF;
        H4u m = h4min(cen, shl1(cen, lw));
        m = h4min(m, shr1(cen, rx));
        m = h4min(m, h4min(ylo, yhi));
        m = h4min(m, h4min(zlo, zhi));
        if (zp < 0 || !yIn || !gxin) m = HP4;
        if (lr < RROW && c < 14) E1c[SLOT3(zp)][lr][c] = m;
        return m;
    };

    // ---- prologue ----
    stageWrite(z0 - 3, stageLoad(z0 - 3));
    stageWrite(z0 - 2, stageLoad(z0 - 2));
    stageWrite(z0 - 1, stageLoad(z0 - 1));
    stageWrite(z0,     stageLoad(z0));
    ldsbar();
    H4u aT, a1, a2 = HP4;
    H4u e1m2 = e1compute(z0 - 2, aT);
    H4u e1m1 = e1compute(z0 - 1, aT);
    ldsbar();
    stageWrite(z0 + 1, stageLoad(z0 + 1));
    ldsbar();
    H4u e1c = e1compute(z0, a1);
    stageWrite(z0 + 2, stageLoad(z0 + 2));
    ldsbar();

    H4u e1m3 = HP4;
    H4u e2c = HN4, e2m1 = HN4;
    H4u zm1_prev = HN4, zm2_prev = HN4;
    H4u skA = HZ4, sq1 = HZ4, sq2 = HZ4;

    // ---- main loop: one LDS barrier per step ----
    for (int z = z0; z <= z1 + 2; ++z) {
        const bool doStage = (z <= z1 - 1);
        H4u stv = doStage ? stageLoad(z + 3) : HP4;
        H4u skN = HZ4;
        if (!FIRST && z < z1 && uAct)
            skN = *(const H4u*)(Sv + (size_t)z * ZS + gyo * YS + gx);

        H4u aC = HP4;
        H4u e1new = (z <= z1) ? e1compute(z + 1, aC) : HP4;

        H4u zm1w;
        {
            H4u t0 = (z >= 1) ? e1m1 : HN4;
            H4u t2 = (z + 1 < NZ) ? e1new : HN4;
            zm1w = h4max(t0, h4max(e1c, t2));
            if (!yIn || !gxin) zm1w = HN4;
            if (lr < RROW && c < 14) ZM1[SLOT2(z)][lr][c] = zm1w;
        }

        const int p = z - 1;
        H4u e2new = HN4;
        if (p >= 0 && p <= z1 && p < NZ) {
            H4u cen = e1m1;
            H4u zlo = e1m2;
            H4u zhi = e1c;
            H4u ylo = E1c[SLOT3(p)][rdn][cc];
            H4u yhi = E1c[SLOT3(p)][rup][cc];
            unsigned lwE = __shfl_up(cen.hi, 1) >> 16;
            unsigned rxE = __shfl_down(cen.lo, 1) & 0xFFFFu;
            if (c == 0) lwE = HINF;
            H4u m2 = h4min(cen, shl1(cen, lwE));
            m2 = h4min(m2, shr1(cen, rxE));
            m2 = h4min(m2, h4min(ylo, yhi));
            m2 = h4min(m2, h4min(zlo, zhi));
            if (yIn && gxin) {
                e2new = m2;
                if (p >= z0 && p < z1 && lr >= 2 && lr <= 25 && c >= 1 && c <= 12)
                    *(H4u*)(Ev + (size_t)p * ZS + gyo * YS + gx) = m2;
            }
        }

        H4u zm2w = h4max(e2m1, h4max(e2c, e2new));
        if (lr < RROW && c < 14) ZM2[SLOT2(z - 2)][lr][c] = zm2w;

        H4u spnew = HZ4;
        if (p >= z0 && p < z1) {
            H4u vm = h4max(ZM1[SLOT2(p)][rdn][cc],
                     h4max(zm1_prev, ZM1[SLOT2(p)][rup][cc]));
            unsigned lw = __shfl_up(vm.hi, 1) >> 16;
            unsigned rx = __shfl_down(vm.lo, 1) & 0xFFFFu;
            if (xlo && c == 1)  lw = HNINF;
            if (xhi && c == 12) rx = HNINF;
            if (uAct) {
                H4u dilh = h4max(h4max(shl1(vm, lw), vm), shr1(vm, rx));
                spnew = h4skel(skA, a2, dilh);
            }
        }

        const int q = z - 3;
        if (q >= z0 && q < z1) {
            H4u vm2 = h4max(ZM2[SLOT2(q)][rdn][cc],
                      h4max(zm2_prev, ZM2[SLOT2(q)][rup][cc]));
            unsigned lw = __shfl_up(vm2.hi, 1) >> 16;
            unsigned rx = __shfl_down(vm2.lo, 1) & 0xFFFFu;
            if (xlo && c == 1)  lw = HNINF;
            if (xhi && c == 12) rx = HNINF;
            if (uAct) {
                H4u dilh = h4max(h4max(shl1(vm2, lw), vm2), shr1(vm2, rx));
                H4u s = h4skel(sq2, e1m3, dilh);
                *(H4u*)(Sv + (size_t)q * ZS + gyo * YS + gx) = s;
            }
        }

        if (doStage) stageWrite(z + 3, stv);

        ldsbar();
        e1m3 = e1m2; e1m2 = e1m1; e1m1 = e1c; e1c = e1new;
        e2m1 = e2c; e2c = e2new;
        zm1_prev = zm1w; zm2_prev = zm2w;
        a2 = a1; a1 = aC;
        sq2 = sq1; sq1 = spnew; skA = skN;
    }
}

// ---------------- LAST kernel (round 50 + fused reduction), 512-thread -----
__global__ __launch_bounds__(512, 8) void last_kernel(
    const _Float16* __restrict__ Ain,
    const float* __restrict__ pred, const float* __restrict__ target,
    const _Float16* __restrict__ skel, double* __restrict__ sums)
{
    __shared__ H4u As[4][R2A][NG];
    __shared__ H4u ZM1[2][RROW][NG];
    __shared__ double sred[16];

    const int tid = threadIdx.x;
    const int lr  = tid >> 4;
    const int c   = tid & 15;
    const int cc  = (c < 14) ? c : 13;
    const int lre = (lr < RROW) ? lr : (RROW - 1);
    const int sr  = tid / 14;
    const int sg  = tid - sr * 14;

    const int x0 = blockIdx.x * TX;
    const int y0 = blockIdx.y * TYB;
    const int v  = blockIdx.z / NCH;
    const int ch = blockIdx.z % NCH;
    const int z0 = ch * ZCHM;
    const int z1 = z0 + ZCHM;

    const _Float16* Ah = Ain + (size_t)v * VOL;
    const _Float16* Sv = skel + (size_t)v * VOL;
    const float* Ov = ((v < 2) ? target : pred) + (size_t)((v & 1) * 2 + 1) * VOL;

    const H4u HP4 = { 0x7C007C00u, 0x7C007C00u };
    const H4u HN4 = { 0xFC00FC00u, 0xFC00FC00u };
    const H4u HZ4 = { 0u, 0u };
    const float4 ZERO4 = make_float4(0.f, 0.f, 0.f, 0.f);

    const bool xlo = (x0 == 0);
    const bool xhi = (x0 + TX == NX);

    const int  gys  = y0 - 3 + sr;
    const int  gxs  = x0 - 4 + 4 * sg;
    const bool stIn = (sr < R2A) && (gys >= 0) && (gys < NY) &&
                      (gxs >= 0) && (gxs < NX);

    const int  gx   = x0 - 4 + 4 * c;
    const bool gxin = (c < 14) && (gx >= 0) && (gx < NX);
    const int  gyo  = y0 - 2 + lre;
    const bool yIn  = (gyo >= 0) && (gyo < NY);
    const bool uAct = (lr >= 2 && lr <= 25 && c >= 1 && c <= 12);
    const int  rdn  = (lre > 0) ? lre - 1 : 0;
    const int  rup  = (lre < RROW - 1) ? lre + 1 : (RROW - 1);

    auto stageLoad = [&](int za) -> H4u {
        H4u val = HP4;
        if (stIn && za >= 0 && za < NZ)
            val = *(const H4u*)(Ah + (size_t)za * ZS + gys * YS + gxs);
        return val;
    };
    auto stageWrite = [&](int za, H4u val) {
        if (sr < R2A) As[SLOT4(za)][sr][sg] = val;
    };

    auto e1compute = [&](int zp, H4u& cenOut) -> H4u {
        if (zp >= NZ) { cenOut = HP4; return HP4; }
        const int s_c = SLOT4(zp), s_m = SLOT4(zp - 1), s_p = SLOT4(zp + 1);
        const bool hp = (zp + 1 < NZ);
        const int ar = lre + 1;
        H4u cen = As[s_c][ar][cc];
        H4u ylo = As[s_c][ar - 1][cc];
        H4u yhi = As[s_c][ar + 1][cc];
        H4u zlo = As[s_m][ar][cc];
        H4u zhi = hp ? As[s_p][ar][cc] : HP4;
        cenOut = cen;
        unsigned lw = __shfl_up(cen.hi, 1) >> 16;
        unsigned rx = __shfl_down(cen.lo, 1) & 0xFFFFu;
        if (c == 0) lw = HINF;
        H4u m = h4min(cen, shl1(cen, lw));
        m = h4min(m, shr1(cen, rx));
        m = h4min(m, h4min(ylo, yhi));
        m = h4min(m, h4min(zlo, zhi));
        if (zp < 0 || !yIn || !gxin) m = HP4;
        return m;
    };

    stageWrite(z0 - 2, stageLoad(z0 - 2));
    stageWrite(z0 - 1, stageLoad(z0 - 1));
    stageWrite(z0,     stageLoad(z0));
    stageWrite(z0 + 1, stageLoad(z0 + 1));
    ldsbar();
    H4u aT, a1, a2 = HP4;
    H4u e1m1 = e1compute(z0 - 1, aT);
    H4u e1c  = e1compute(z0, a1);
    ldsbar();
    stageWrite(z0 + 2, stageLoad(z0 + 2));
    ldsbar();

    H4u zmP = HN4;
    H4u skA = HZ4;
    float4 oA = ZERO4;
    double afd = 0.0, afs = 0.0;

    for (int z = z0; z <= z1; ++z) {
        const bool doStage = (z <= z1 - 2);
        H4u stv = doStage ? stageLoad(z + 3) : HP4;
        H4u skN = HZ4;
        float4 oN = ZERO4;
        if (z < z1 && uAct) {
            skN = *(const H4u*)(Sv + (size_t)z * ZS + gyo * YS + gx);
            oN  = *(const float4*)(Ov + (size_t)z * ZS + gyo * YS + gx);
        }

        H4u aC = HP4;
        H4u e1new = (z + 1 <= z1) ? e1compute(z + 1, aC) : HP4;

        H4u zm1w = HN4;
        if (z <= z1 - 1) {
            H4u t0 = (z >= 1) ? e1m1 : HN4;
            H4u t2 = (z + 1 < NZ) ? e1new : HN4;
            zm1w = h4max(t0, h4max(e1c, t2));
            if (!yIn || !gxin) zm1w = HN4;
            if (lr < RROW && c < 14) ZM1[SLOT2(z)][lr][c] = zm1w;
        }

        const int p = z - 1;
        if (p >= z0 && p < z1) {
            H4u vm = h4max(ZM1[SLOT2(p)][rdn][cc],
                     h4max(zmP, ZM1[SLOT2(p)][rup][cc]));
            unsigned lw = __shfl_up(vm.hi, 1) >> 16;
            unsigned rx = __shfl_down(vm.lo, 1) & 0xFFFFu;
            if (xlo && c == 1)  lw = HNINF;
            if (xhi && c == 12) rx = HNINF;
            if (uAct) {
                H4u dilh = h4max(h4max(shl1(vm, lw), vm), shr1(vm, rx));
                H4u s = h4skel(skA, a2, dilh);
                float4 sf = h4_to_f4(s);
                afd += (double)(sf.x * oA.x + sf.y * oA.y +
                                sf.z * oA.z + sf.w * oA.w);
                afs += (double)(sf.x + sf.y + sf.z + sf.w);
            }
        }

        if (doStage) stageWrite(z + 3, stv);

        ldsbar();
        e1m1 = e1c; e1c = e1new;
        a2 = a1; a1 = aC;
        zmP = zm1w;
        skA = skN; oA = oN;
    }

#pragma unroll
    for (int off = 32; off > 0; off >>= 1) {
        afd += __shfl_down(afd, off, 64);
        afs += __shfl_down(afs, off, 64);
    }
    int lane = tid & 63, wid = tid >> 6;
    if (lane == 0) { sred[wid * 2] = afd; sred[wid * 2 + 1] = afs; }
    __syncthreads();
    if (tid == 0) {
        double fd = 0.0, fs = 0.0;
#pragma unroll
        for (int w = 0; w < 8; ++w) { fd += sred[w * 2]; fs += sred[w * 2 + 1]; }
        if (v < 2) { atomicAdd(&sums[0], fd); atomicAdd(&sums[1], fs); }
        else       { atomicAdd(&sums[2], fd); atomicAdd(&sums[3], fs); }
    }
}

__global__ void final_kernel(const double* __restrict__ sums,
                             float* __restrict__ out) {
    if (threadIdx.x == 0 && blockIdx.x == 0) {
        const double SM = 1e-5;
        double tprec = (sums[0] + SM) / (sums[1] + SM);
        double tsens = (sums[2] + SM) / (sums[3] + SM);
        double cl = 2.0 * tprec * tsens / (tprec + tsens + SM);
        out[0] = (float)(1.0 - cl);
    }
}

extern "C" void kernel_launch(void* const* d_in, const int* in_sizes, int n_in,
                              void* d_out, int out_size, void* d_ws, size_t ws_size,
                              hipStream_t stream) {
    const float* pred = (const float*)d_in[0];
    const float* target = (const float*)d_in[1];
    float* out = (float*)d_out;

    _Float16* H0 = (_Float16*)d_ws;
    _Float16* H1 = H0 + NTOT;
    _Float16* skel = H1 + NTOT;
    double* sums = (double*)(skel + NTOT);

    hipMemsetAsync(sums, 0, 4 * sizeof(double), stream);

    dim3 g(NX / TX, NY / TYB, NV * NCH);     /* 4 x 8 x 32 = 1024 blocks */

    /* rounds 0,1: FIRST (reads pred/target channels directly) */
    fused2_kernel<true><<<g, 512, 0, stream>>>(pred, target, H0, H0, skel);
    /* rounds 2..49: 24 double launches */
    _Float16* A = H0;
    _Float16* B = H1;
    for (int j = 0; j < 24; ++j) {
        fused2_kernel<false><<<g, 512, 0, stream>>>(pred, target, A, B, skel);
        _Float16* t = A; A = B; B = t;
    }
    /* round 50 + fused reduction */
    last_kernel<<<g, 512, 0, stream>>>(A, pred, target, skel, sums);

    final_kernel<<<1, 64, 0, stream>>>(sums, out);
}